// Round 6
// baseline (177.374 us; speedup 1.0000x reference)
//
#include <hip/hip_runtime.h>
#include <stdint.h>

#define KW   128   // u32 words per row (4096 bits)
#define BM   128   // tile rows (tokens)
#define BN    64   // tile cols (out features)
#define NCK    4   // K chunks: 4 x 8 uint4 (1024 bits) each

// ---------------------------------------------------------------------------
// Binarize: wave of 64 lanes reads 64 consecutive floats, ballot(v>0) gives a
// 64-bit mask in exact lane order; lane 0 stores the u64.
// ---------------------------------------------------------------------------
__global__ __launch_bounds__(256) void binarize64(const float* __restrict__ in,
                                                  unsigned long long* __restrict__ out,
                                                  int n64) {
    const int tid   = blockIdx.x * blockDim.x + threadIdx.x;
    const int lane  = threadIdx.x & 63;
    const int wave  = tid >> 6;
    const int nwav  = (gridDim.x * blockDim.x) >> 6;
    for (int w = wave; w < n64; w += nwav) {
        float v = in[(size_t)w * 64 + lane];
        unsigned long long m = __ballot(v > 0.0f);
        if (lane == 0) out[w] = m;
    }
}

// ---------------------------------------------------------------------------
// Binary GEMM: C[i][j] = 4096 - 2 * popcount(row_i(xb) ^ row_j(wb))
// 128x64 tile, 256 threads (16x16), 8x4 micro-tile. K chunked: 4 x 1024 bits,
// LDS 24 KB.
// Accumulate is PLAIN C (`acc += __popc(x^y)`): LLVM folds add(ctpop) into
// v_bcnt_u32_b32, and with no inline-asm register-class constraint the
// AGPR-homed accumulator is encoded directly as the VALU operand (CDNA allows
// AGPR operands on VALU). R4/R5's inline asm with "+v" forced
// accvgpr_read/write copy pairs around every accumulate = 2x VALU.
// LDS swizzle: chunk cw of row r stored at cw ^ ((r>>3)&7). Thread's 8 A rows
// share key ty&7; its 4 B rows share key tx>>1 -> per-j addressing is two
// v_xor, element offsets are immediates.
// ---------------------------------------------------------------------------
__global__ __launch_bounds__(256, 2) void xnor_gemm(const uint32_t* __restrict__ xb,
                                                    const uint32_t* __restrict__ wb,
                                                    float* __restrict__ out) {
    __shared__ uint4 lA[BM * 8];   // 16 KB
    __shared__ uint4 lB[BN * 8];   // 8 KB

    const int tid  = threadIdx.x;
    const int brow = blockIdx.y;
    const int bcol = blockIdx.x;
    const int tx   = tid & 15;     // col group: 4 cols
    const int ty   = tid >> 4;     // row group: 8 rows

    // global bases in uint4 units (full row = 32 uint4)
    const uint4* gA = (const uint4*)xb + (size_t)(brow * BM) * 32;
    const uint4* gB = (const uint4*)wb + (size_t)(bcol * BN) * 32;

    // staging decomposition
    const int sr  = tid >> 3;      // 0..31
    const int scw = tid & 7;       // 0..7

    uint32_t acc[8][4];
#pragma unroll
    for (int r = 0; r < 8; ++r)
#pragma unroll
        for (int c = 0; c < 4; ++c) acc[r][c] = 0;

    const uint4* pa = lA + ty * 64;    // row ty*8, 8 uint4/row
    const uint4* pb = lB + tx * 32;    // row tx*4
    const int ka = ty & 7;             // shared swizzle key for 8 A rows
    const int kb = tx >> 1;            // shared swizzle key for 4 B rows

    for (int ck = 0; ck < NCK; ++ck) {
        if (ck) __syncthreads();
#pragma unroll
        for (int k = 0; k < 4; ++k) {          // A: 128 rows
            const int r = sr + k * 32;
            lA[r * 8 + (scw ^ ((r >> 3) & 7))] = gA[(size_t)r * 32 + ck * 8 + scw];
        }
#pragma unroll
        for (int k = 0; k < 2; ++k) {          // B: 64 rows
            const int r = sr + k * 32;
            lB[r * 8 + (scw ^ ((r >> 3) & 7))] = gB[(size_t)r * 32 + ck * 8 + scw];
        }
        __syncthreads();

        // ---- compute: 8 j-steps; per j: 12 b128 reads + 256 fused VALU -----
#pragma unroll 1
        for (int j = 0; j < 8; ++j) {
            const uint4* paj = pa + (j ^ ka);   // 1 v_xor
            const uint4* pbj = pb + (j ^ kb);   // 1 v_xor
            uint4 a[8], b[4];
#pragma unroll
            for (int r = 0; r < 8; ++r) a[r] = paj[r * 8];   // imm offsets
#pragma unroll
            for (int c = 0; c < 4; ++c) b[c] = pbj[c * 8];
#pragma unroll
            for (int r = 0; r < 8; ++r)
#pragma unroll
                for (int c = 0; c < 4; ++c) {
                    acc[r][c] += __popc(a[r].x ^ b[c].x);   // v_xor + v_bcnt(acc)
                    acc[r][c] += __popc(a[r].y ^ b[c].y);
                    acc[r][c] += __popc(a[r].z ^ b[c].z);
                    acc[r][c] += __popc(a[r].w ^ b[c].w);
                }
        }
    }

    // ---- epilogue: dot = 4096 - 2*popc, float4 stores ----------------------
    const size_t N = 4096;
    const int gcol = bcol * BN + tx * 4;
#pragma unroll
    for (int r = 0; r < 8; ++r) {
        const size_t grow = (size_t)(brow * BM + ty * 8 + r);
        float4 o;
        o.x = (float)(4096 - 2 * (int)acc[r][0]);
        o.y = (float)(4096 - 2 * (int)acc[r][1]);
        o.z = (float)(4096 - 2 * (int)acc[r][2]);
        o.w = (float)(4096 - 2 * (int)acc[r][3]);
        *(float4*)(out + grow * N + gcol) = o;
    }
}

extern "C" void kernel_launch(void* const* d_in, const int* in_sizes, int n_in,
                              void* d_out, int out_size, void* d_ws, size_t ws_size,
                              hipStream_t stream) {
    const float* x = (const float*)d_in[0];   // [4096, 4096]
    const float* W = (const float*)d_in[1];   // [4096, 4096] (out, in)
    float* out = (float*)d_out;               // [4096, 4096] f32

    uint32_t* xb = (uint32_t*)d_ws;            // 2 MB
    uint32_t* wb = xb + (size_t)4096 * KW;     // next 2 MB

    const int n64 = 4096 * 4096 / 64;
    binarize64<<<2048, 256, 0, stream>>>(x, (unsigned long long*)xb, n64);
    binarize64<<<2048, 256, 0, stream>>>(W, (unsigned long long*)wb, n64);

    dim3 grid(4096 / BN, 4096 / BM);           // 64 x 32 blocks
    xnor_gemm<<<grid, 256, 0, stream>>>(xb, wb, out);
}

// Round 8
// 151.697 us; speedup vs baseline: 1.1693x; 1.1693x over previous
//
#include <hip/hip_runtime.h>
#include <stdint.h>

#define KW   128   // u32 words per row (4096 bits)
#define BM   128   // tile rows (tokens)
#define BN    64   // tile cols (out features)
#define NCK    4   // K chunks: 4 x 8 uint4 (1024 bits) each

// ---------------------------------------------------------------------------
// Binarize: wave of 64 lanes reads 64 consecutive floats, ballot(v>0) gives a
// 64-bit mask in exact lane order; lane 0 stores the u64.
// ---------------------------------------------------------------------------
__global__ __launch_bounds__(256) void binarize64(const float* __restrict__ in,
                                                  unsigned long long* __restrict__ out,
                                                  int n64) {
    const int tid   = blockIdx.x * blockDim.x + threadIdx.x;
    const int lane  = threadIdx.x & 63;
    const int wave  = tid >> 6;
    const int nwav  = (gridDim.x * blockDim.x) >> 6;
    for (int w = wave; w < n64; w += nwav) {
        float v = in[(size_t)w * 64 + lane];
        unsigned long long m = __ballot(v > 0.0f);
        if (lane == 0) out[w] = m;
    }
}

// 4-word popcount-accumulate, one asm block:
//   4x v_xor + 4x CHAINED v_bcnt seeded by acc = exactly 8 insts / 4 words,
//   and acc is touched ONCE per 4 words (R1/R5/R6 post-mortem: allocator
//   homes acc[] in AGPRs; v_bcnt can't encode AGPRs (R7 compile error), so
//   every acc touch risks an accvgpr_read/write pair. Batching 4 words per
//   touch caps the worst-case tax at 2 copies / 4 words = 2.5 ops/word vs 4).
static __device__ __forceinline__ void pacc4(uint32_t& acc, const uint4& a, const uint4& b) {
    uint32_t t0, t1, t2, t3;
    asm("v_xor_b32 %1, %5, %9\n\t"
        "v_xor_b32 %2, %6, %10\n\t"
        "v_xor_b32 %3, %7, %11\n\t"
        "v_xor_b32 %4, %8, %12\n\t"
        "v_bcnt_u32_b32 %0, %1, %0\n\t"
        "v_bcnt_u32_b32 %0, %2, %0\n\t"
        "v_bcnt_u32_b32 %0, %3, %0\n\t"
        "v_bcnt_u32_b32 %0, %4, %0"
        : "+v"(acc), "=&v"(t0), "=&v"(t1), "=&v"(t2), "=&v"(t3)
        : "v"(a.x), "v"(a.y), "v"(a.z), "v"(a.w),
          "v"(b.x), "v"(b.y), "v"(b.z), "v"(b.w));
}

// ---------------------------------------------------------------------------
// Binary GEMM: C[i][j] = 4096 - 2 * popcount(row_i(xb) ^ row_j(wb))
// 128x64 tile, 256 threads (16x16), 8x4 micro-tile. K chunked: 4 x 1024 bits,
// LDS 24 KB.
// LDS swizzle: chunk cw of row r stored at cw ^ ((r>>3)&7). Thread's 8 A rows
// share key ty&7; its 4 B rows share key tx>>1 -> per-j addressing is two
// v_xor, element offsets are immediates.
// ---------------------------------------------------------------------------
__global__ __launch_bounds__(256, 2) void xnor_gemm(const uint32_t* __restrict__ xb,
                                                    const uint32_t* __restrict__ wb,
                                                    float* __restrict__ out) {
    __shared__ uint4 lA[BM * 8];   // 16 KB
    __shared__ uint4 lB[BN * 8];   // 8 KB

    const int tid  = threadIdx.x;
    const int brow = blockIdx.y;
    const int bcol = blockIdx.x;
    const int tx   = tid & 15;     // col group: 4 cols
    const int ty   = tid >> 4;     // row group: 8 rows

    // global bases in uint4 units (full row = 32 uint4)
    const uint4* gA = (const uint4*)xb + (size_t)(brow * BM) * 32;
    const uint4* gB = (const uint4*)wb + (size_t)(bcol * BN) * 32;

    // staging decomposition
    const int sr  = tid >> 3;      // 0..31
    const int scw = tid & 7;       // 0..7

    uint32_t acc[8][4];
#pragma unroll
    for (int r = 0; r < 8; ++r)
#pragma unroll
        for (int c = 0; c < 4; ++c) acc[r][c] = 0;

    const uint4* pa = lA + ty * 64;    // row ty*8, 8 uint4/row
    const uint4* pb = lB + tx * 32;    // row tx*4
    const int ka = ty & 7;             // shared swizzle key for 8 A rows
    const int kb = tx >> 1;            // shared swizzle key for 4 B rows

    for (int ck = 0; ck < NCK; ++ck) {
        if (ck) __syncthreads();
#pragma unroll
        for (int k = 0; k < 4; ++k) {          // A: 128 rows
            const int r = sr + k * 32;
            lA[r * 8 + (scw ^ ((r >> 3) & 7))] = gA[(size_t)r * 32 + ck * 8 + scw];
        }
#pragma unroll
        for (int k = 0; k < 2; ++k) {          // B: 64 rows
            const int r = sr + k * 32;
            lB[r * 8 + (scw ^ ((r >> 3) & 7))] = gB[(size_t)r * 32 + ck * 8 + scw];
        }
        __syncthreads();

        // ---- compute: 8 j-steps; per j: 12 b128 reads + 32 pacc4 (256 insts)
#pragma unroll 1
        for (int j = 0; j < 8; ++j) {
            const uint4* paj = pa + (j ^ ka);   // 1 v_xor
            const uint4* pbj = pb + (j ^ kb);   // 1 v_xor
            uint4 a[8], b[4];
#pragma unroll
            for (int r = 0; r < 8; ++r) a[r] = paj[r * 8];   // imm offsets
#pragma unroll
            for (int c = 0; c < 4; ++c) b[c] = pbj[c * 8];
#pragma unroll
            for (int r = 0; r < 8; ++r)
#pragma unroll
                for (int c = 0; c < 4; ++c)
                    pacc4(acc[r][c], a[r], b[c]);
        }
    }

    // ---- epilogue: dot = 4096 - 2*popc, float4 stores ----------------------
    const size_t N = 4096;
    const int gcol = bcol * BN + tx * 4;
#pragma unroll
    for (int r = 0; r < 8; ++r) {
        const size_t grow = (size_t)(brow * BM + ty * 8 + r);
        float4 o;
        o.x = (float)(4096 - 2 * (int)acc[r][0]);
        o.y = (float)(4096 - 2 * (int)acc[r][1]);
        o.z = (float)(4096 - 2 * (int)acc[r][2]);
        o.w = (float)(4096 - 2 * (int)acc[r][3]);
        *(float4*)(out + grow * N + gcol) = o;
    }
}

extern "C" void kernel_launch(void* const* d_in, const int* in_sizes, int n_in,
                              void* d_out, int out_size, void* d_ws, size_t ws_size,
                              hipStream_t stream) {
    const float* x = (const float*)d_in[0];   // [4096, 4096]
    const float* W = (const float*)d_in[1];   // [4096, 4096] (out, in)
    float* out = (float*)d_out;               // [4096, 4096] f32

    uint32_t* xb = (uint32_t*)d_ws;            // 2 MB
    uint32_t* wb = xb + (size_t)4096 * KW;     // next 2 MB

    const int n64 = 4096 * 4096 / 64;
    binarize64<<<2048, 256, 0, stream>>>(x, (unsigned long long*)xb, n64);
    binarize64<<<2048, 256, 0, stream>>>(W, (unsigned long long*)wb, n64);

    dim3 grid(4096 / BN, 4096 / BM);           // 64 x 32 blocks
    xnor_gemm<<<grid, 256, 0, stream>>>(xb, wb, out);
}

// Round 9
// 108.401 us; speedup vs baseline: 1.6363x; 1.3994x over previous
//
#include <hip/hip_runtime.h>
#include <stdint.h>

typedef __attribute__((ext_vector_type(4))) int int32x4;

#define PK_TILE_U32 131072   // one 128-row packed tile = 512 KB = 131072 u32

// ---------------------------------------------------------------------------
// sign_pack: f32 -> i8 (+1/-1), blocked k-major layout:
//   [tile = row/128][chunk = k/16][row % 128][16 bytes]
// so each GEMM K-step (64 k = 4 chunks) is one LINEAR 8 KB block:
// perfect global_load_lds coalescing and conflict-free k-major LDS.
// Wave reads 1 KB contiguous (one row x 256 cols); lane packs 4 i8 into u32.
// ---------------------------------------------------------------------------
__global__ __launch_bounds__(256) void sign_pack(const float* __restrict__ in,
                                                 uint32_t* __restrict__ outp) {
    const int lane = threadIdx.x & 63;
    const int wave = (blockIdx.x * blockDim.x + threadIdx.x) >> 6;
    const int nw   = (gridDim.x * blockDim.x) >> 6;
    for (int it = wave; it < 4096 * 16; it += nw) {
        const int row = it >> 4;
        const int col = ((it & 15) << 8) + lane * 4;
        float4 v = *(const float4*)(in + (size_t)row * 4096 + col);
        uint32_t w = (v.x > 0.f ? 1u : 0xFFu)
                   | ((v.y > 0.f ? 1u : 0xFFu) << 8)
                   | ((v.z > 0.f ? 1u : 0xFFu) << 16)
                   | ((v.w > 0.f ? 1u : 0xFFu) << 24);
        const int tile = row >> 7, rl = row & 127;
        const int chunk = col >> 4;          // k/16
        const int word  = (col >> 2) & 3;    // u32 within 16B slot
        outp[(size_t)tile * PK_TILE_U32 + chunk * 512 + rl * 4 + word] = w;
    }
}

// ---------------------------------------------------------------------------
// i8 MFMA GEMM: C[i][j] = sum_k sx[i][k]*sw[j][k], exact in i32.
// 128x128 tile, 4 waves; wave (wr,wc) owns 64x64 = 4x4 MFMA 16x16 tiles.
// K-step 64 (4 chunks); LDS [4 chunks][128 rows][16B] per matrix (8 KB),
// staged with 2x global_load_lds(16B) per matrix per step (linear copy from
// the blocked layout). Frag reads: lanes 0-15 span 256 contiguous LDS bytes
// -> conflict-free. 1024 blocks = exactly 4/CU resident.
// A-frag: row = lane&15, k-chunk = lane>>4.  C/D: col = lane&15,
// row = (lane>>4)*4 + reg  (guide-verified, dtype-independent).
// ---------------------------------------------------------------------------
__global__ void i8_gemm(const uint32_t* __restrict__ xp,
                        const uint32_t* __restrict__ wp,
                        float* __restrict__ out) {
    __shared__ uint4 lA4[512];   // 8 KB
    __shared__ uint4 lB4[512];   // 8 KB
    uint8_t* lA = (uint8_t*)lA4;
    uint8_t* lB = (uint8_t*)lB4;

    const int tid  = threadIdx.x;
    const int lane = tid & 63;
    const int wv   = tid >> 6;
    const int wr   = wv >> 1, wc = wv & 1;
    const int brow = blockIdx.y, bcol = blockIdx.x;

    const uint8_t* gA = (const uint8_t*)(xp + (size_t)brow * PK_TILE_U32);
    const uint8_t* gB = (const uint8_t*)(wp + (size_t)bcol * PK_TILE_U32);

    int32x4 acc[4][4];
#pragma unroll
    for (int m = 0; m < 4; ++m)
#pragma unroll
        for (int n = 0; n < 4; ++n) acc[m][n] = (int32x4){0, 0, 0, 0};

    const int ldsw = wv * 1024;                       // wave-uniform dest base
    const uint8_t* pA = lA + (lane >> 4) * 2048 + (wr * 64 + (lane & 15)) * 16;
    const uint8_t* pB = lB + (lane >> 4) * 2048 + (wc * 64 + (lane & 15)) * 16;

    for (int ks = 0; ks < 64; ++ks) {
        const uint8_t* sa = gA + ks * 8192 + tid * 16;
        const uint8_t* sb = gB + ks * 8192 + tid * 16;
        __builtin_amdgcn_global_load_lds(
            (const __attribute__((address_space(1))) uint32_t*)sa,
            (__attribute__((address_space(3))) uint32_t*)(lA + ldsw), 16, 0, 0);
        __builtin_amdgcn_global_load_lds(
            (const __attribute__((address_space(1))) uint32_t*)(sa + 4096),
            (__attribute__((address_space(3))) uint32_t*)(lA + ldsw + 4096), 16, 0, 0);
        __builtin_amdgcn_global_load_lds(
            (const __attribute__((address_space(1))) uint32_t*)sb,
            (__attribute__((address_space(3))) uint32_t*)(lB + ldsw), 16, 0, 0);
        __builtin_amdgcn_global_load_lds(
            (const __attribute__((address_space(1))) uint32_t*)(sb + 4096),
            (__attribute__((address_space(3))) uint32_t*)(lB + ldsw + 4096), 16, 0, 0);
        __syncthreads();   // drains vmcnt (loads landed) + lds visibility

        int32x4 a[4], b[4];
#pragma unroll
        for (int m = 0; m < 4; ++m) a[m] = *(const int32x4*)(pA + m * 256);
#pragma unroll
        for (int n = 0; n < 4; ++n) b[n] = *(const int32x4*)(pB + n * 256);
#pragma unroll
        for (int m = 0; m < 4; ++m)
#pragma unroll
            for (int n = 0; n < 4; ++n)
                acc[m][n] = __builtin_amdgcn_mfma_i32_16x16x64_i8(
                    a[m], b[n], acc[m][n], 0, 0, 0);
        __syncthreads();   // frags consumed before restage
    }

    // epilogue: i32 -> f32 exact
    const int orow = brow * 128 + wr * 64 + (lane >> 4) * 4;
    const int ocol = bcol * 128 + wc * 64 + (lane & 15);
#pragma unroll
    for (int m = 0; m < 4; ++m)
#pragma unroll
        for (int reg = 0; reg < 4; ++reg) {
            const size_t rb = (size_t)(orow + m * 16 + reg) * 4096 + ocol;
#pragma unroll
            for (int n = 0; n < 4; ++n)
                out[rb + n * 16] = (float)acc[m][n][reg];
        }
}

// ======================= fallback (R8 binary path) =========================
__global__ __launch_bounds__(256) void binarize64(const float* __restrict__ in,
                                                  unsigned long long* __restrict__ out,
                                                  int n64) {
    const int tid  = blockIdx.x * blockDim.x + threadIdx.x;
    const int lane = threadIdx.x & 63;
    const int wave = tid >> 6;
    const int nwav = (gridDim.x * blockDim.x) >> 6;
    for (int w = wave; w < n64; w += nwav) {
        float v = in[(size_t)w * 64 + lane];
        unsigned long long m = __ballot(v > 0.0f);
        if (lane == 0) out[w] = m;
    }
}

static __device__ __forceinline__ void pacc4(uint32_t& acc, const uint4& a, const uint4& b) {
    uint32_t t0, t1, t2, t3;
    asm("v_xor_b32 %1, %5, %9\n\t"
        "v_xor_b32 %2, %6, %10\n\t"
        "v_xor_b32 %3, %7, %11\n\t"
        "v_xor_b32 %4, %8, %12\n\t"
        "v_bcnt_u32_b32 %0, %1, %0\n\t"
        "v_bcnt_u32_b32 %0, %2, %0\n\t"
        "v_bcnt_u32_b32 %0, %3, %0\n\t"
        "v_bcnt_u32_b32 %0, %4, %0"
        : "+v"(acc), "=&v"(t0), "=&v"(t1), "=&v"(t2), "=&v"(t3)
        : "v"(a.x), "v"(a.y), "v"(a.z), "v"(a.w),
          "v"(b.x), "v"(b.y), "v"(b.z), "v"(b.w));
}

__global__ __launch_bounds__(256, 2) void xnor_gemm(const uint32_t* __restrict__ xb,
                                                    const uint32_t* __restrict__ wb,
                                                    float* __restrict__ out) {
    __shared__ uint4 lA[128 * 8];
    __shared__ uint4 lB[64 * 8];
    const int tid  = threadIdx.x;
    const int brow = blockIdx.y, bcol = blockIdx.x;
    const int tx = tid & 15, ty = tid >> 4;
    const uint4* gA = (const uint4*)xb + (size_t)(brow * 128) * 32;
    const uint4* gB = (const uint4*)wb + (size_t)(bcol * 64) * 32;
    const int sr = tid >> 3, scw = tid & 7;
    uint32_t acc[8][4];
#pragma unroll
    for (int r = 0; r < 8; ++r)
#pragma unroll
        for (int c = 0; c < 4; ++c) acc[r][c] = 0;
    const uint4* pa = lA + ty * 64;
    const uint4* pb = lB + tx * 32;
    const int ka = ty & 7, kb = tx >> 1;
    for (int ck = 0; ck < 4; ++ck) {
        if (ck) __syncthreads();
#pragma unroll
        for (int k = 0; k < 4; ++k) {
            const int r = sr + k * 32;
            lA[r * 8 + (scw ^ ((r >> 3) & 7))] = gA[(size_t)r * 32 + ck * 8 + scw];
        }
#pragma unroll
        for (int k = 0; k < 2; ++k) {
            const int r = sr + k * 32;
            lB[r * 8 + (scw ^ ((r >> 3) & 7))] = gB[(size_t)r * 32 + ck * 8 + scw];
        }
        __syncthreads();
#pragma unroll 1
        for (int j = 0; j < 8; ++j) {
            const uint4* paj = pa + (j ^ ka);
            const uint4* pbj = pb + (j ^ kb);
            uint4 a[8], b[4];
#pragma unroll
            for (int r = 0; r < 8; ++r) a[r] = paj[r * 8];
#pragma unroll
            for (int c = 0; c < 4; ++c) b[c] = pbj[c * 8];
#pragma unroll
            for (int r = 0; r < 8; ++r)
#pragma unroll
                for (int c = 0; c < 4; ++c) pacc4(acc[r][c], a[r], b[c]);
        }
    }
    const int gcol = bcol * 64 + tx * 4;
#pragma unroll
    for (int r = 0; r < 8; ++r) {
        const size_t grow = (size_t)(brow * 128 + ty * 8 + r);
        float4 o;
        o.x = (float)(4096 - 2 * (int)acc[r][0]);
        o.y = (float)(4096 - 2 * (int)acc[r][1]);
        o.z = (float)(4096 - 2 * (int)acc[r][2]);
        o.w = (float)(4096 - 2 * (int)acc[r][3]);
        *(float4*)(out + grow * 4096 + gcol) = o;
    }
}

extern "C" void kernel_launch(void* const* d_in, const int* in_sizes, int n_in,
                              void* d_out, int out_size, void* d_ws, size_t ws_size,
                              hipStream_t stream) {
    const float* x = (const float*)d_in[0];   // [4096, 4096]
    const float* W = (const float*)d_in[1];   // [4096, 4096] (out, in)
    float* out = (float*)d_out;               // [4096, 4096] f32

    if (ws_size >= 2u * 16777216u) {
        // MFMA i8 path: needs 32 MB workspace
        uint32_t* xp = (uint32_t*)d_ws;                 // 16 MB packed x
        uint32_t* wpk = xp + (size_t)4194304;           // 16 MB packed W
        sign_pack<<<2048, 256, 0, stream>>>(x, xp);
        sign_pack<<<2048, 256, 0, stream>>>(W, wpk);
        dim3 grid(32, 32);
        i8_gemm<<<grid, 256, 0, stream>>>(xp, wpk, out);
    } else {
        // fallback: binary xor-popcount path (needs 4 MB)
        uint32_t* xb = (uint32_t*)d_ws;
        uint32_t* wb = xb + (size_t)4096 * 128;
        const int n64 = 4096 * 4096 / 64;
        binarize64<<<2048, 256, 0, stream>>>(x, (unsigned long long*)xb, n64);
        binarize64<<<2048, 256, 0, stream>>>(W, (unsigned long long*)wb, n64);
        dim3 grid(64, 32);
        xnor_gemm<<<grid, 256, 0, stream>>>(xb, wb, out);
    }
}